// Round 5
// baseline (233.210 us; speedup 1.0000x reference)
//
#include <hip/hip_runtime.h>

// y[n] = beta0 + sum_c X[n,c]*(beta[c] + Z[n,c]),  Z = X @ triu(Theta,1)
// R5: conv passes (X->bf16, Theta->triu^T bf16) into d_ws; GEMM is 256x256
// 8-wave with the m201-style PER-PHASE interleave: each K-tile (BK=32) is two
// phases of {ds_read subtile | stage half-tile | barrier | lgkmcnt(0) |
// setprio(1) 16xMFMA setprio(0) | barrier}, counted vmcnt(8) once per K-tile
// (never 0 in steady state), 4 LDS buffers depth-3. Zero-conflict k-plane LDS
// layout (R4-verified). L2-aware XCD group mapping (2bm x 4bn per group).

typedef __bf16 bf16_t;
typedef bf16_t bf16x8 __attribute__((ext_vector_type(8)));
typedef float f32x4 __attribute__((ext_vector_type(4)));
typedef unsigned short u16;
typedef u16 u16x4 __attribute__((ext_vector_type(4)));
typedef u16 u16x8 __attribute__((ext_vector_type(8)));

#define N_ROWS 65536
#define P_DIM  1024
#define BM 256
#define BN 256
#define BK 32
#define NBUF 4
#define BUF_U16 16384    // 32 KB per buffer (A 8192 u16 + B 8192 u16)
#define PLANE_U16 2048   // one 16B k-quarter plane: 256 rows * 8 u16

static __device__ __forceinline__ u16 f2bf(float f) {
  unsigned u = __builtin_bit_cast(unsigned, f);
  u += 0x7FFFu + ((u >> 16) & 1u);   // round-to-nearest-even
  return (u16)(u >> 16);
}
static __device__ __forceinline__ float bf2f(u16 v) {
  return __builtin_bit_cast(float, ((unsigned)v) << 16);
}

// global(16B/lane) -> LDS direct. LDS dest must be WAVE-UNIFORM base; HW adds lane*16.
static __device__ __forceinline__ void gload16(const void* g, void* lds_base) {
  __builtin_amdgcn_global_load_lds(
      (const __attribute__((address_space(1))) unsigned char*)g,
      (__attribute__((address_space(3))) unsigned char*)lds_base, 16, 0, 0);
}

__global__ void __launch_bounds__(256)
init_y(float* __restrict__ y, const float* __restrict__ beta0) {
  int i = blockIdx.x * blockDim.x + threadIdx.x;
  if (i < N_ROWS) y[i] = beta0[0];
}

// ---- conversion pass 1: X f32 -> bf16 ----
__global__ void __launch_bounds__(256)
conv_x(const float* __restrict__ X, u16* __restrict__ Xb) {
  const size_t total8 = (size_t)N_ROWS * P_DIM / 8;
  const size_t stride = (size_t)gridDim.x * 256;
  for (size_t i = (size_t)blockIdx.x * 256 + threadIdx.x; i < total8; i += stride) {
    f32x4 a = *(const f32x4*)(X + i * 8);
    f32x4 b = *(const f32x4*)(X + i * 8 + 4);
    u16x8 w;
    #pragma unroll
    for (int j = 0; j < 4; ++j) { w[j] = f2bf(a[j]); w[j + 4] = f2bf(b[j]); }
    *(u16x8*)(Xb + i * 8) = w;
  }
}

// ---- conversion pass 2: Tt[c][k] = (k<c) ? bf16(Theta[k][c]) : 0 ----
__global__ void __launch_bounds__(256)
conv_theta(const float* __restrict__ Theta, u16* __restrict__ Tt) {
  __shared__ float tile[32][33];
  const int tx = threadIdx.x;          // 0..31
  const int ty = threadIdx.y;          // 0..7
  const int k0 = blockIdx.x * 32;
  const int c0 = blockIdx.y * 32;
  #pragma unroll
  for (int i = 0; i < 4; ++i) {
    int kl = ty + 8 * i;
    tile[kl][tx] = Theta[(size_t)(k0 + kl) * P_DIM + c0 + tx];
  }
  __syncthreads();
  #pragma unroll
  for (int i = 0; i < 4; ++i) {
    int cl = ty + 8 * i;
    int c = c0 + cl, k = k0 + tx;
    float v = tile[tx][cl];
    Tt[(size_t)c * P_DIM + k] = (k < c) ? f2bf(v) : (u16)0;
  }
}

// ---- main GEMM + fused epilogue: 256x256, 8 waves, 8-phase pipeline ----
__global__ void __launch_bounds__(512, 2)
gemm_bf16_8ph(const u16* __restrict__ Xb, const u16* __restrict__ Tt,
              const float* __restrict__ beta, float* __restrict__ y)
{
  __shared__ __align__(16) u16 L[NBUF * BUF_U16];   // 128 KB

  // L2-aware XCD group mapping: per XCD, groups of 8 blocks = {2 bm} x {4 bn},
  // heavy (bn=3) first within each group. Concurrent working set per XCD:
  // ~8 A-panels (4 MB) + full Tt (2 MB) ~= L2. Uniform group composition
  // (160 K-tiles each) keeps CUs balanced (80 K-tile units per CU).
  const int bid = blockIdx.x;          // 0..1023
  const int xcd = bid & 7;
  const int j   = bid >> 3;            // 0..127
  const int g   = j >> 3;              // 0..15
  const int e   = j & 7;               // 0..7
  const int bm  = xcd * 32 + g * 2 + (e & 1);
  const int bn  = 3 - (e >> 1);        // 3,3,2,2,1,1,0,0
  const int c0  = bn * BN;
  const int m0  = bm * BM;
  const int nt  = (bn + 1) * (BN / BK);   // triangular K-skip: 8,16,24,32 tiles

  const int tid  = threadIdx.x;
  const int lane = tid & 63;
  const int wid  = tid >> 6;           // 0..7
  const int wm   = wid >> 2;           // 0..1  (M half: 128 rows)
  const int wn   = wid & 3;            // 0..3  (N quarter: 64 cols)
  const int l15  = lane & 15;
  const int lg   = lane >> 4;

  // staging geometry (R4-verified, 0 bank conflicts): 16 chunks of 1 KB per
  // operand; chunk c = k-plane (c>>2), rows [(c&3)*64,+64); LDS dest linear,
  // k-plane permutation lives in the per-lane GLOBAL source address.
  int rowA[2], rowB[2], pof[2];
  #pragma unroll
  for (int q = 0; q < 2; ++q) {
    const int c = wid * 2 + q;
    rowA[q] = m0 + (c & 3) * 64 + lane;
    rowB[q] = c0 + (c & 3) * 64 + lane;
    pof[q]  = (c >> 2) * 8;
  }
  // frag read bases (u16 index): plane lg, row (wm*128|wn*64) + l15
  const int pA = lg * PLANE_U16 + (wm * 128 + l15) * 8;
  const int pB = 8192 + lg * PLANE_U16 + (wn * 64 + l15) * 8;

  f32x4 acc[8][4];
  #pragma unroll
  for (int i = 0; i < 8; ++i)
    #pragma unroll
    for (int j2 = 0; j2 < 4; ++j2)
      acc[i][j2] = (f32x4)0.0f;

  #define STAGE_A(buf_, t_)                                                       \
    {                                                                             \
      const int kk_ = (t_) * BK;                                                  \
      const int b_  = (buf_) * BUF_U16;                                           \
      _Pragma("unroll")                                                           \
      for (int q = 0; q < 2; ++q) {                                               \
        const int cc_ = wid * 2 + q;                                              \
        gload16(Xb + (size_t)rowA[q] * P_DIM + kk_ + pof[q], &L[b_ + cc_ * 512]); \
      }                                                                           \
    }
  #define STAGE_B(buf_, t_)                                                       \
    {                                                                             \
      const int kk_ = (t_) * BK;                                                  \
      const int b_  = (buf_) * BUF_U16;                                           \
      _Pragma("unroll")                                                           \
      for (int q = 0; q < 2; ++q) {                                               \
        const int cc_ = wid * 2 + q;                                              \
        gload16(Tt + (size_t)rowB[q] * P_DIM + kk_ + pof[q], &L[b_ + 8192 + cc_ * 512]); \
      }                                                                           \
    }

  // prologue: fill pipeline 3 deep (12 loads/thread outstanding)
  STAGE_A(0, 0) STAGE_B(0, 0)
  STAGE_A(1, 1) STAGE_B(1, 1)
  STAGE_A(2, 2) STAGE_B(2, 2)
  asm volatile("s_waitcnt vmcnt(8)" ::: "memory");   // tile 0 (mine) landed
  __builtin_amdgcn_sched_barrier(0);
  __builtin_amdgcn_s_barrier();                      // everyone's tile 0 landed
  __builtin_amdgcn_sched_barrier(0);

  for (int t = 0; t < nt; ++t) {
    const int bb = (t & 3) * BUF_U16;
    bf16x8 af0[4], af1[4], bfrag[4];

    // ================= phase 0 =================
    #pragma unroll
    for (int mi = 0; mi < 4; ++mi) {
      u16x8 v = *(const u16x8*)&L[bb + pA + mi * 128];
      af0[mi] = __builtin_bit_cast(bf16x8, v);
    }
    #pragma unroll
    for (int ni = 0; ni < 4; ++ni) {
      u16x8 v = *(const u16x8*)&L[bb + pB + ni * 128];
      bfrag[ni] = __builtin_bit_cast(bf16x8, v);
    }
    if (t + 3 < nt) STAGE_A((t + 3) & 3, t + 3)   // into buf freed at end of t-1

    __builtin_amdgcn_sched_barrier(0);
    __builtin_amdgcn_s_barrier();
    asm volatile("s_waitcnt lgkmcnt(0)" ::: "memory");
    __builtin_amdgcn_sched_barrier(0);
    __builtin_amdgcn_s_setprio(1);
    #pragma unroll
    for (int mi = 0; mi < 4; ++mi)
      #pragma unroll
      for (int ni = 0; ni < 4; ++ni)
        acc[mi][ni] = __builtin_amdgcn_mfma_f32_16x16x32_bf16(af0[mi], bfrag[ni], acc[mi][ni], 0, 0, 0);
    __builtin_amdgcn_s_setprio(0);
    __builtin_amdgcn_sched_barrier(0);
    __builtin_amdgcn_s_barrier();

    // ================= phase 1 =================
    #pragma unroll
    for (int mi = 0; mi < 4; ++mi) {
      u16x8 v = *(const u16x8*)&L[bb + pA + (mi + 4) * 128];
      af1[mi] = __builtin_bit_cast(bf16x8, v);
    }
    if (t + 3 < nt) STAGE_B((t + 3) & 3, t + 3)

    // counted wait, once per K-tile: tile t+1's 4 loads landed; t+2/t+3 in flight
    if (t + 3 < nt) {
      asm volatile("s_waitcnt vmcnt(8)" ::: "memory");
    } else if (t + 2 < nt) {
      asm volatile("s_waitcnt vmcnt(4)" ::: "memory");
    } else if (t + 1 < nt) {
      asm volatile("s_waitcnt vmcnt(0)" ::: "memory");
    }
    __builtin_amdgcn_sched_barrier(0);
    __builtin_amdgcn_s_barrier();
    asm volatile("s_waitcnt lgkmcnt(0)" ::: "memory");
    __builtin_amdgcn_sched_barrier(0);
    __builtin_amdgcn_s_setprio(1);
    #pragma unroll
    for (int mi = 0; mi < 4; ++mi)
      #pragma unroll
      for (int ni = 0; ni < 4; ++ni)
        acc[mi + 4][ni] = __builtin_amdgcn_mfma_f32_16x16x32_bf16(af1[mi], bfrag[ni], acc[mi + 4][ni], 0, 0, 0);
    __builtin_amdgcn_s_setprio(0);
    __builtin_amdgcn_sched_barrier(0);
    __builtin_amdgcn_s_barrier();
  }
  #undef STAGE_A
  #undef STAGE_B

  // ---- epilogue: y_partial[row] = sum_c (Z[row,c] + beta[c]) * X[row,c] ----
  // C/D layout (16x16): col = lane&15, row = (lane>>4)*4 + reg
  float ysum[8][4];
  #pragma unroll
  for (int mi = 0; mi < 8; ++mi)
    #pragma unroll
    for (int r = 0; r < 4; ++r)
      ysum[mi][r] = 0.0f;

  #pragma unroll
  for (int ni = 0; ni < 4; ++ni) {
    const int col = c0 + wn * 64 + ni * 16 + l15;
    const float bta = beta[col];
    #pragma unroll
    for (int mi = 0; mi < 8; ++mi) {
      const int rowb = m0 + wm * 128 + mi * 16 + lg * 4;
      #pragma unroll
      for (int r = 0; r < 4; ++r) {
        float xv = bf2f(Xb[(size_t)(rowb + r) * P_DIM + col]);   // L2-hot
        ysum[mi][r] += (acc[mi][ni][r] + bta) * xv;
      }
    }
  }

  #pragma unroll
  for (int m = 1; m < 16; m <<= 1)
    #pragma unroll
    for (int mi = 0; mi < 8; ++mi)
      #pragma unroll
      for (int r = 0; r < 4; ++r)
        ysum[mi][r] += __shfl_xor(ysum[mi][r], m);

  if (l15 == 0) {
    #pragma unroll
    for (int mi = 0; mi < 8; ++mi)
      #pragma unroll
      for (int r = 0; r < 4; ++r)
        atomicAdd(&y[m0 + wm * 128 + mi * 16 + lg * 4 + r], ysum[mi][r]);
  }
}

// ================= fallback (R1 kernel, 128x128) if ws too small =================
#define LDT 40
__global__ void __launch_bounds__(256)
fused_quad_fallback(const float* __restrict__ X, const float* __restrict__ beta,
                    const float* __restrict__ Theta, float* __restrict__ y)
{
  __shared__ __align__(16) u16 Alds[128 * LDT];
  __shared__ __align__(16) u16 Blds[128 * LDT];

  const int bid = blockIdx.x;
  const int bn  = bid & 7;
  const int bm  = bid >> 3;
  const int c0  = bn * 128;
  const int m0  = bm * 128;
  const int nkt = (bn + 1) * 4;

  const int tid  = threadIdx.x;
  const int lane = tid & 63;
  const int wid  = tid >> 6;
  const int wm   = wid >> 1;
  const int wn   = wid & 1;
  const int l15  = lane & 15;
  const int lg   = lane >> 4;

  f32x4 acc[4][4];
  #pragma unroll
  for (int i = 0; i < 4; ++i)
    #pragma unroll
    for (int j = 0; j < 4; ++j)
      acc[i][j] = (f32x4)0.0f;

  const int arow  = tid >> 1;
  const int ahalf = (tid & 1) * 16;
  const int kb4 = (tid >> 5) * 4;
  const int cb4 = (tid & 31) * 4;

  for (int kt = 0; kt < nkt; ++kt) {
    const int k0 = kt * 32;
    __syncthreads();
    {
      const f32x4* p = (const f32x4*)(X + (size_t)(m0 + arow) * P_DIM + k0 + ahalf);
      f32x4 v0 = p[0], v1 = p[1], v2 = p[2], v3 = p[3];
      u16x8 w0, w1;
      #pragma unroll
      for (int i = 0; i < 4; ++i) {
        w0[i] = f2bf(v0[i]); w0[i + 4] = f2bf(v1[i]);
        w1[i] = f2bf(v2[i]); w1[i + 4] = f2bf(v3[i]);
      }
      *(u16x8*)&Alds[arow * LDT + ahalf]     = w0;
      *(u16x8*)&Alds[arow * LDT + ahalf + 8] = w1;
    }
    {
      float e[4][4];
      #pragma unroll
      for (int i = 0; i < 4; ++i) {
        f32x4 r = *(const f32x4*)(Theta + (size_t)(k0 + kb4 + i) * P_DIM + c0 + cb4);
        #pragma unroll
        for (int j = 0; j < 4; ++j)
          e[i][j] = ((k0 + kb4 + i) < (c0 + cb4 + j)) ? r[j] : 0.0f;
      }
      #pragma unroll
      for (int j = 0; j < 4; ++j) {
        u16x4 wv;
        #pragma unroll
        for (int i = 0; i < 4; ++i) wv[i] = f2bf(e[i][j]);
        *(u16x4*)&Blds[(cb4 + j) * LDT + kb4] = wv;
      }
    }
    __syncthreads();

    bf16x8 af[4], bfr[4];
    #pragma unroll
    for (int mi = 0; mi < 4; ++mi) {
      u16x8 t = *(const u16x8*)&Alds[(wm * 64 + mi * 16 + l15) * LDT + lg * 8];
      af[mi] = __builtin_bit_cast(bf16x8, t);
    }
    #pragma unroll
    for (int ni = 0; ni < 4; ++ni) {
      u16x8 t = *(const u16x8*)&Blds[(wn * 64 + ni * 16 + l15) * LDT + lg * 8];
      bfr[ni] = __builtin_bit_cast(bf16x8, t);
    }
    #pragma unroll
    for (int mi = 0; mi < 4; ++mi)
      #pragma unroll
      for (int ni = 0; ni < 4; ++ni)
        acc[mi][ni] = __builtin_amdgcn_mfma_f32_16x16x32_bf16(af[mi], bfr[ni], acc[mi][ni], 0, 0, 0);
  }

  float ysum[4][4];
  #pragma unroll
  for (int mi = 0; mi < 4; ++mi)
    #pragma unroll
    for (int r = 0; r < 4; ++r)
      ysum[mi][r] = 0.0f;

  #pragma unroll
  for (int ni = 0; ni < 4; ++ni) {
    const int col = c0 + wn * 64 + ni * 16 + l15;
    const float bta = beta[col];
    #pragma unroll
    for (int mi = 0; mi < 4; ++mi) {
      const int rowb = m0 + wm * 64 + mi * 16 + lg * 4;
      #pragma unroll
      for (int r = 0; r < 4; ++r) {
        float xv = X[(size_t)(rowb + r) * P_DIM + col];
        ysum[mi][r] += (acc[mi][ni][r] + bta) * xv;
      }
    }
  }

  #pragma unroll
  for (int m = 1; m < 16; m <<= 1)
    #pragma unroll
    for (int mi = 0; mi < 4; ++mi)
      #pragma unroll
      for (int r = 0; r < 4; ++r)
        ysum[mi][r] += __shfl_xor(ysum[mi][r], m);

  if (l15 == 0) {
    #pragma unroll
    for (int mi = 0; mi < 4; ++mi)
      #pragma unroll
      for (int r = 0; r < 4; ++r)
        atomicAdd(&y[m0 + wm * 64 + mi * 16 + lg * 4 + r], ysum[mi][r]);
  }
}

extern "C" void kernel_launch(void* const* d_in, const int* in_sizes, int n_in,
                              void* d_out, int out_size, void* d_ws, size_t ws_size,
                              hipStream_t stream) {
  const float* X     = (const float*)d_in[0];
  const float* beta0 = (const float*)d_in[1];
  const float* beta  = (const float*)d_in[2];
  const float* Theta = (const float*)d_in[3];
  float* y = (float*)d_out;

  init_y<<<N_ROWS / 256, 256, 0, stream>>>(y, beta0);

  const size_t need = (size_t)N_ROWS * P_DIM * 2 + (size_t)P_DIM * P_DIM * 2;
  if (ws_size >= need) {
    u16* Xb = (u16*)d_ws;
    u16* Tt = Xb + (size_t)N_ROWS * P_DIM;
    conv_x<<<2048, 256, 0, stream>>>(X, Xb);
    conv_theta<<<dim3(32, 32), dim3(32, 8), 0, stream>>>(Theta, Tt);
    gemm_bf16_8ph<<<(N_ROWS / BM) * (P_DIM / BN), 512, 0, stream>>>(Xb, Tt, beta, y);
  } else {
    fused_quad_fallback<<<(N_ROWS / 128) * (P_DIM / 128), 256, 0, stream>>>(X, beta, Theta, y);
  }
}

// Round 6
// 215.344 us; speedup vs baseline: 1.0830x; 1.0830x over previous
//
#include <hip/hip_runtime.h>

// y[n] = beta0 + sum_c X[n,c]*(beta[c] + Z[n,c]),  Z = X @ triu(Theta,1)
// R6: conv passes (X->bf16, Theta->triu^T bf16) into d_ws. GEMM 256x256,
// 8 waves, BK=32, depth-3 counted-vmcnt pipeline (R4 schedule) with
// COALESCED staging: row-major [256][32] LDS tiles, chunk = 16 rows x 32 k,
// 4 lanes per 64B row-segment (16 lines/instr vs 64 in R4/R5). Frag
// ds_read_b128 is bank-optimal (8-sweep minimum) without swizzle.
// Epilogue: X-block restaged into LDS (coalesced, XOR-swizzled) and read
// scattered from LDS instead of 128 uncoalesced global loads per thread.

typedef __bf16 bf16_t;
typedef bf16_t bf16x8 __attribute__((ext_vector_type(8)));
typedef float f32x4 __attribute__((ext_vector_type(4)));
typedef unsigned short u16;
typedef u16 u16x4 __attribute__((ext_vector_type(4)));
typedef u16 u16x8 __attribute__((ext_vector_type(8)));

#define N_ROWS 65536
#define P_DIM  1024
#define BM 256
#define BN 256
#define BK 32
#define NBUF 4
#define BUF_U16 16384    // 32 KB per buffer: A [256][32] u16 + B [256][32] u16

static __device__ __forceinline__ u16 f2bf(float f) {
  unsigned u = __builtin_bit_cast(unsigned, f);
  u += 0x7FFFu + ((u >> 16) & 1u);   // round-to-nearest-even
  return (u16)(u >> 16);
}
static __device__ __forceinline__ float bf2f(u16 v) {
  return __builtin_bit_cast(float, ((unsigned)v) << 16);
}

// global(16B/lane) -> LDS direct. LDS dest must be WAVE-UNIFORM base; HW adds lane*16.
static __device__ __forceinline__ void gload16(const void* g, void* lds_base) {
  __builtin_amdgcn_global_load_lds(
      (const __attribute__((address_space(1))) unsigned char*)g,
      (__attribute__((address_space(3))) unsigned char*)lds_base, 16, 0, 0);
}

__global__ void __launch_bounds__(256)
init_y(float* __restrict__ y, const float* __restrict__ beta0) {
  int i = blockIdx.x * blockDim.x + threadIdx.x;
  if (i < N_ROWS) y[i] = beta0[0];
}

// ---- conversion pass 1: X f32 -> bf16 ----
__global__ void __launch_bounds__(256)
conv_x(const float* __restrict__ X, u16* __restrict__ Xb) {
  const size_t total8 = (size_t)N_ROWS * P_DIM / 8;
  const size_t stride = (size_t)gridDim.x * 256;
  for (size_t i = (size_t)blockIdx.x * 256 + threadIdx.x; i < total8; i += stride) {
    f32x4 a = *(const f32x4*)(X + i * 8);
    f32x4 b = *(const f32x4*)(X + i * 8 + 4);
    u16x8 w;
    #pragma unroll
    for (int j = 0; j < 4; ++j) { w[j] = f2bf(a[j]); w[j + 4] = f2bf(b[j]); }
    *(u16x8*)(Xb + i * 8) = w;
  }
}

// ---- conversion pass 2: Tt[c][k] = (k<c) ? bf16(Theta[k][c]) : 0 ----
__global__ void __launch_bounds__(256)
conv_theta(const float* __restrict__ Theta, u16* __restrict__ Tt) {
  __shared__ float tile[32][33];
  const int tx = threadIdx.x;          // 0..31
  const int ty = threadIdx.y;          // 0..7
  const int k0 = blockIdx.x * 32;
  const int c0 = blockIdx.y * 32;
  #pragma unroll
  for (int i = 0; i < 4; ++i) {
    int kl = ty + 8 * i;
    tile[kl][tx] = Theta[(size_t)(k0 + kl) * P_DIM + c0 + tx];
  }
  __syncthreads();
  #pragma unroll
  for (int i = 0; i < 4; ++i) {
    int cl = ty + 8 * i;
    int c = c0 + cl, k = k0 + tx;
    float v = tile[tx][cl];
    Tt[(size_t)c * P_DIM + k] = (k < c) ? f2bf(v) : (u16)0;
  }
}

// ---- main GEMM + fused epilogue: 256x256, 8 waves, depth-3, coalesced ----
__global__ void __launch_bounds__(512, 2)
gemm_bf16_r6(const u16* __restrict__ Xb, const u16* __restrict__ Tt,
             const float* __restrict__ beta, float* __restrict__ y)
{
  __shared__ __align__(16) u16 L[NBUF * BUF_U16];   // 128 KB

  // L2-aware XCD group mapping (R5): per XCD, groups of 8 = {2 bm} x {4 bn},
  // heavy bn first; ~6 MB concurrent working set per XCD; balanced CUs.
  const int bid = blockIdx.x;          // 0..1023
  const int xcd = bid & 7;
  const int j   = bid >> 3;            // 0..127
  const int g   = j >> 3;              // 0..15
  const int e   = j & 7;               // 0..7
  const int bm  = xcd * 32 + g * 2 + (e & 1);
  const int bn  = 3 - (e >> 1);        // 3,3,2,2,1,1,0,0
  const int c0  = bn * BN;
  const int m0  = bm * BM;
  const int nt  = (bn + 1) * (BN / BK);   // triangular K-skip: 8,16,24,32 tiles

  const int tid  = threadIdx.x;
  const int lane = tid & 63;
  const int wid  = tid >> 6;           // 0..7
  const int wm   = wid >> 2;           // 0..1  (M half: 128 rows)
  const int wn   = wid & 3;            // 0..3  (N quarter: 64 cols)
  const int l15  = lane & 15;
  const int lg   = lane >> 4;

  // staging geometry: chunk = 16 rows x 32 k = 1 KB. lane l -> row c*16+(l>>2),
  // k-quarter (l&3)*8. 4 consecutive lanes read 64 B contiguous (coalesced:
  // 16 lines/instr). LDS dest linear row-major [256][32] u16.
  const int srow = lane >> 2;          // 0..15 (row within chunk)
  const int skq  = (lane & 3) * 8;     // k element offset 0,8,16,24

  // frag read bases (u16 idx, row-major [256][32]): A row (wm*128 + mi*16 + l15),
  // B row (wn*64 + ni*16 + l15), k = lg*8.
  const int pA = (wm * 128 + l15) * 32 + lg * 8;
  const int pB = 8192 + (wn * 64 + l15) * 32 + lg * 8;

  f32x4 acc[8][4];
  #pragma unroll
  for (int i = 0; i < 8; ++i)
    #pragma unroll
    for (int j2 = 0; j2 < 4; ++j2)
      acc[i][j2] = (f32x4)0.0f;

  #define STAGE(buf_, t_)                                                        \
    {                                                                            \
      const int kk_ = (t_) * BK;                                                 \
      const int b_  = (buf_) * BUF_U16;                                          \
      _Pragma("unroll")                                                          \
      for (int q = 0; q < 2; ++q) {                                              \
        const int c_ = wid * 2 + q;                                              \
        const int r_ = c_ * 16 + srow;                                           \
        gload16(Xb + (size_t)(m0 + r_) * P_DIM + kk_ + skq, &L[b_ + c_ * 512]);  \
        gload16(Tt + (size_t)(c0 + r_) * P_DIM + kk_ + skq, &L[b_ + 8192 + c_ * 512]); \
      }                                                                          \
    }

  // prologue: fill pipeline 3 deep (12 loads/thread outstanding)
  STAGE(0, 0)
  STAGE(1, 1)
  STAGE(2, 2)
  asm volatile("s_waitcnt vmcnt(8)" ::: "memory");   // my tile-0 loads landed
  __builtin_amdgcn_sched_barrier(0);
  __builtin_amdgcn_s_barrier();                      // everyone's tile 0 landed
  __builtin_amdgcn_sched_barrier(0);

  for (int t = 0; t < nt; ++t) {
    const int bb = (t & 3) * BUF_U16;

    // issue prefetch FIRST (TA busy while LDS serves frags); dest buffer was
    // freed by iter t-1's end barrier.
    if (t + 3 < nt) STAGE((t + 3) & 3, t + 3)

    bf16x8 af[8], bfrag[4];
    #pragma unroll
    for (int mi = 0; mi < 8; ++mi) {
      u16x8 v = *(const u16x8*)&L[bb + pA + mi * (16 * 32)];
      af[mi] = __builtin_bit_cast(bf16x8, v);
    }
    #pragma unroll
    for (int ni = 0; ni < 4; ++ni) {
      u16x8 v = *(const u16x8*)&L[bb + pB + ni * (16 * 32)];
      bfrag[ni] = __builtin_bit_cast(bf16x8, v);
    }

    __builtin_amdgcn_s_setprio(1);
    #pragma unroll
    for (int mi = 0; mi < 8; ++mi)
      #pragma unroll
      for (int ni = 0; ni < 4; ++ni)
        acc[mi][ni] = __builtin_amdgcn_mfma_f32_16x16x32_bf16(af[mi], bfrag[ni], acc[mi][ni], 0, 0, 0);
    __builtin_amdgcn_s_setprio(0);

    // counted wait: tile t+1's 4 loads landed; t+2/t+3 stay in flight
    if (t + 3 < nt) {
      asm volatile("s_waitcnt vmcnt(8)" ::: "memory");
    } else if (t + 2 < nt) {
      asm volatile("s_waitcnt vmcnt(4)" ::: "memory");
    } else if (t + 1 < nt) {
      asm volatile("s_waitcnt vmcnt(0)" ::: "memory");
    }
    __builtin_amdgcn_sched_barrier(0);
    __builtin_amdgcn_s_barrier();
    __builtin_amdgcn_sched_barrier(0);
  }
  #undef STAGE

  // ---- epilogue: restage X block [256][256] bf16 into LDS (128 KB), coalesced,
  // with 8-chunk XOR swizzle: lds(row,col) = row*256 + ((col>>3)^(row&7))*8 + (col&7).
  // Stage chunk ch = 2 rows (1 KB): lane l -> row 2ch+(l>>5), slot s=l&31 holds
  // global col-chunk s^(row&7) (same 512 B row span -> coalescing preserved).
  {
    #pragma unroll
    for (int i = 0; i < 16; ++i) {
      const int ch  = wid * 16 + i;          // 0..127
      const int row = 2 * ch + (lane >> 5);
      const int s   = lane & 31;
      gload16(Xb + (size_t)(m0 + row) * P_DIM + c0 + ((s ^ (row & 7)) * 8),
              &L[ch * 512]);
    }
    asm volatile("s_waitcnt vmcnt(0)" ::: "memory");
    __builtin_amdgcn_sched_barrier(0);
    __builtin_amdgcn_s_barrier();
    __builtin_amdgcn_sched_barrier(0);
  }

  // y_partial[row] = sum_c (Z[row,c] + beta[c]) * X[row,c]
  // C/D layout (16x16): col = lane&15, row = (lane>>4)*4 + reg
  float ysum[8][4];
  #pragma unroll
  for (int mi = 0; mi < 8; ++mi)
    #pragma unroll
    for (int r = 0; r < 4; ++r)
      ysum[mi][r] = 0.0f;

  #pragma unroll
  for (int ni = 0; ni < 4; ++ni) {
    const int colr = wn * 64 + ni * 16 + l15;
    const float bta = beta[c0 + colr];
    #pragma unroll
    for (int mi = 0; mi < 8; ++mi) {
      #pragma unroll
      for (int r = 0; r < 4; ++r) {
        const int rowr = wm * 128 + mi * 16 + lg * 4 + r;
        float xv = bf2f(L[rowr * 256 + (((colr >> 3) ^ (rowr & 7)) * 8) + (colr & 7)]);
        ysum[mi][r] += (acc[mi][ni][r] + bta) * xv;
      }
    }
  }

  #pragma unroll
  for (int m = 1; m < 16; m <<= 1)
    #pragma unroll
    for (int mi = 0; mi < 8; ++mi)
      #pragma unroll
      for (int r = 0; r < 4; ++r)
        ysum[mi][r] += __shfl_xor(ysum[mi][r], m);

  if (l15 == 0) {
    #pragma unroll
    for (int mi = 0; mi < 8; ++mi)
      #pragma unroll
      for (int r = 0; r < 4; ++r)
        atomicAdd(&y[m0 + wm * 128 + mi * 16 + lg * 4 + r], ysum[mi][r]);
  }
}

// ================= fallback (R1 kernel, 128x128) if ws too small =================
#define LDT 40
__global__ void __launch_bounds__(256)
fused_quad_fallback(const float* __restrict__ X, const float* __restrict__ beta,
                    const float* __restrict__ Theta, float* __restrict__ y)
{
  __shared__ __align__(16) u16 Alds[128 * LDT];
  __shared__ __align__(16) u16 Blds[128 * LDT];

  const int bid = blockIdx.x;
  const int bn  = bid & 7;
  const int bm  = bid >> 3;
  const int c0  = bn * 128;
  const int m0  = bm * 128;
  const int nkt = (bn + 1) * 4;

  const int tid  = threadIdx.x;
  const int lane = tid & 63;
  const int wid  = tid >> 6;
  const int wm   = wid >> 1;
  const int wn   = wid & 1;
  const int l15  = lane & 15;
  const int lg   = lane >> 4;

  f32x4 acc[4][4];
  #pragma unroll
  for (int i = 0; i < 4; ++i)
    #pragma unroll
    for (int j = 0; j < 4; ++j)
      acc[i][j] = (f32x4)0.0f;

  const int arow  = tid >> 1;
  const int ahalf = (tid & 1) * 16;
  const int kb4 = (tid >> 5) * 4;
  const int cb4 = (tid & 31) * 4;

  for (int kt = 0; kt < nkt; ++kt) {
    const int k0 = kt * 32;
    __syncthreads();
    {
      const f32x4* p = (const f32x4*)(X + (size_t)(m0 + arow) * P_DIM + k0 + ahalf);
      f32x4 v0 = p[0], v1 = p[1], v2 = p[2], v3 = p[3];
      u16x8 w0, w1;
      #pragma unroll
      for (int i = 0; i < 4; ++i) {
        w0[i] = f2bf(v0[i]); w0[i + 4] = f2bf(v1[i]);
        w1[i] = f2bf(v2[i]); w1[i + 4] = f2bf(v3[i]);
      }
      *(u16x8*)&Alds[arow * LDT + ahalf]     = w0;
      *(u16x8*)&Alds[arow * LDT + ahalf + 8] = w1;
    }
    {
      float e[4][4];
      #pragma unroll
      for (int i = 0; i < 4; ++i) {
        f32x4 r = *(const f32x4*)(Theta + (size_t)(k0 + kb4 + i) * P_DIM + c0 + cb4);
        #pragma unroll
        for (int j = 0; j < 4; ++j)
          e[i][j] = ((k0 + kb4 + i) < (c0 + cb4 + j)) ? r[j] : 0.0f;
      }
      #pragma unroll
      for (int j = 0; j < 4; ++j) {
        u16x4 wv;
        #pragma unroll
        for (int i = 0; i < 4; ++i) wv[i] = f2bf(e[i][j]);
        *(u16x4*)&Blds[(cb4 + j) * LDT + kb4] = wv;
      }
    }
    __syncthreads();

    bf16x8 af[4], bfr[4];
    #pragma unroll
    for (int mi = 0; mi < 4; ++mi) {
      u16x8 t = *(const u16x8*)&Alds[(wm * 64 + mi * 16 + l15) * LDT + lg * 8];
      af[mi] = __builtin_bit_cast(bf16x8, t);
    }
    #pragma unroll
    for (int ni = 0; ni < 4; ++ni) {
      u16x8 t = *(const u16x8*)&Blds[(wn * 64 + ni * 16 + l15) * LDT + lg * 8];
      bfr[ni] = __builtin_bit_cast(bf16x8, t);
    }
    #pragma unroll
    for (int mi = 0; mi < 4; ++mi)
      #pragma unroll
      for (int ni = 0; ni < 4; ++ni)
        acc[mi][ni] = __builtin_amdgcn_mfma_f32_16x16x32_bf16(af[mi], bfr[ni], acc[mi][ni], 0, 0, 0);
  }

  float ysum[4][4];
  #pragma unroll
  for (int mi = 0; mi < 4; ++mi)
    #pragma unroll
    for (int r = 0; r < 4; ++r)
      ysum[mi][r] = 0.0f;

  #pragma unroll
  for (int ni = 0; ni < 4; ++ni) {
    const int col = c0 + wn * 64 + ni * 16 + l15;
    const float bta = beta[col];
    #pragma unroll
    for (int mi = 0; mi < 4; ++mi) {
      const int rowb = m0 + wm * 64 + mi * 16 + lg * 4;
      #pragma unroll
      for (int r = 0; r < 4; ++r) {
        float xv = X[(size_t)(rowb + r) * P_DIM + col];
        ysum[mi][r] += (acc[mi][ni][r] + bta) * xv;
      }
    }
  }

  #pragma unroll
  for (int m = 1; m < 16; m <<= 1)
    #pragma unroll
    for (int mi = 0; mi < 4; ++mi)
      #pragma unroll
      for (int r = 0; r < 4; ++r)
        ysum[mi][r] += __shfl_xor(ysum[mi][r], m);

  if (l15 == 0) {
    #pragma unroll
    for (int mi = 0; mi < 4; ++mi)
      #pragma unroll
      for (int r = 0; r < 4; ++r)
        atomicAdd(&y[m0 + wm * 64 + mi * 16 + lg * 4 + r], ysum[mi][r]);
  }
}

extern "C" void kernel_launch(void* const* d_in, const int* in_sizes, int n_in,
                              void* d_out, int out_size, void* d_ws, size_t ws_size,
                              hipStream_t stream) {
  const float* X     = (const float*)d_in[0];
  const float* beta0 = (const float*)d_in[1];
  const float* beta  = (const float*)d_in[2];
  const float* Theta = (const float*)d_in[3];
  float* y = (float*)d_out;

  init_y<<<N_ROWS / 256, 256, 0, stream>>>(y, beta0);

  const size_t need = (size_t)N_ROWS * P_DIM * 2 + (size_t)P_DIM * P_DIM * 2;
  if (ws_size >= need) {
    u16* Xb = (u16*)d_ws;
    u16* Tt = Xb + (size_t)N_ROWS * P_DIM;
    conv_x<<<2048, 256, 0, stream>>>(X, Xb);
    conv_theta<<<dim3(32, 32), dim3(32, 8), 0, stream>>>(Theta, Tt);
    gemm_bf16_r6<<<(N_ROWS / BM) * (P_DIM / BN), 512, 0, stream>>>(Xb, Tt, beta, y);
  } else {
    fused_quad_fallback<<<(N_ROWS / 128) * (P_DIM / 128), 256, 0, stream>>>(X, beta, Theta, y);
  }
}